// Round 3
// baseline (399.594 us; speedup 1.0000x reference)
//
#include <hip/hip_runtime.h>

// Problem constants (B=2048, F=512, U=512, G=64, REG_STRENGTH=1.0)
#define B_SZ 2048
#define F_SZ 512
#define U_SZ 512
#define G_SZ 64
#define REG_STRENGTH 1.0f

// prep: histogram/prefix/scatter (proven round-0 kernel).
// gemm: one 16x16 output fragment per WAVE. wave = (g, ct, mt):
//   g  = group (64), ct = 16-col tile (32), mt = 16-row m-tile (4).
//   4096 blocks x 128 threads (2 independent waves/block), no LDS, no
//   barriers, branch-free fully-unrolled K loop, split-bf16 3x MFMA.
#define THREADS 128
#define NBLOCKS 4096
#define NWAVES_TOT 8192

typedef float f32x4 __attribute__((ext_vector_type(4)));
typedef __bf16 bf16x8 __attribute__((ext_vector_type(8)));

#define MFMA(a, b, c) __builtin_amdgcn_mfma_f32_16x16x32_bf16((a), (b), (c), 0, 0, 0)

// fp32 -> (hi, lo) bf16 split of 8 values (RNE casts; compiler emits
// v_cvt_pk_bf16_f32). Dropped lo*lo matmul term is O(2^-18).
static __device__ __forceinline__ void cvt8(const f32x4 a, const f32x4 b,
                                            bf16x8& h, bf16x8& l) {
#pragma unroll
  for (int i = 0; i < 4; ++i) {
    const __bf16 hb = (__bf16)a[i];
    h[i] = hb;
    l[i] = (__bf16)(a[i] - (float)hb);
  }
#pragma unroll
  for (int i = 0; i < 4; ++i) {
    const __bf16 hb = (__bf16)b[i];
    h[4 + i] = hb;
    l[4 + i] = (__bf16)(b[i] - (float)hb);
  }
}

// ---------------------------------------------------------------------------
// Kernel A: histogram gid -> counts, prefix sum -> rowstart, scatter -> order.
// ---------------------------------------------------------------------------
__global__ __launch_bounds__(1024) void prep_kernel(
    const int* __restrict__ gid, int* __restrict__ counts,
    int* __restrict__ rowstart, int* __restrict__ order) {
  __shared__ int cnt_s[G_SZ];
  __shared__ int cur_s[G_SZ];
  const int tid = threadIdx.x;

  if (tid < G_SZ) cnt_s[tid] = 0;
  __syncthreads();

  for (int b = tid; b < B_SZ; b += 1024) atomicAdd(&cnt_s[gid[b]], 1);
  __syncthreads();

  if (tid == 0) {
    int run = 0;
    for (int g = 0; g < G_SZ; ++g) { cur_s[g] = run; run += cnt_s[g]; }
  }
  __syncthreads();

  if (tid < G_SZ) { counts[tid] = cnt_s[tid]; rowstart[tid] = cur_s[tid]; }
  __syncthreads();  // snapshot rowstart before scatter mutates cur_s

  for (int b = tid; b < B_SZ; b += 1024) {
    int pos = atomicAdd(&cur_s[gid[b]], 1);
    order[pos] = b;
  }
}

// ---------------------------------------------------------------------------
// Branch-free K loop: 16 chunks of k=32, all offsets compile-time immediates.
// Two parity accumulators break the serial MFMA dependency chain.
// ---------------------------------------------------------------------------
template <bool DOREG>
static __device__ __forceinline__ void kloop(
    const float* __restrict__ wp, const float* __restrict__ w0p,
    const float* __restrict__ xq, f32x4& acc0, f32x4& acc1, float& regp) {
#pragma unroll
  for (int kc = 0; kc < F_SZ; kc += 32) {
    const f32x4 wa = *(const f32x4*)(wp + kc);
    const f32x4 wb = *(const f32x4*)(wp + kc + 4);
    const f32x4 xa = *(const f32x4*)(xq + kc);
    const f32x4 xb = *(const f32x4*)(xq + kc + 4);
    if (DOREG) {  // fused W reg-loss: each W element visited exactly once
      const f32x4 za = *(const f32x4*)(w0p + kc);
      const f32x4 zb = *(const f32x4*)(w0p + kc + 4);
#pragma unroll
      for (int i = 0; i < 4; ++i) {
        const float d0 = wa[i] - za[i], d1 = wb[i] - zb[i];
        regp += d0 * d0 + d1 * d1;
      }
    }
    bf16x8 wh, wl, xh, xl;
    cvt8(wa, wb, wh, wl);
    cvt8(xa, xb, xh, xl);
    f32x4& acc = ((kc & 32) == 0) ? acc0 : acc1;
    acc = MFMA(xh, wh, acc);
    acc = MFMA(xh, wl, acc);
    acc = MFMA(xl, wh, acc);
  }
}

// ---------------------------------------------------------------------------
// Kernel B: grouped GEMM, one 16x16 fragment per wave, fused reg loss +
// finalize. No LDS, no barriers.
// ---------------------------------------------------------------------------
__global__ __launch_bounds__(THREADS, 4) void gemm_kernel(
    const float* __restrict__ x, const float* __restrict__ w_mu,
    const float* __restrict__ b_mu, const float* __restrict__ w0_mu,
    const float* __restrict__ b0_mu, float* __restrict__ out,
    float* __restrict__ wsf, unsigned* __restrict__ done,
    const int* __restrict__ counts, const int* __restrict__ rowstart,
    const int* __restrict__ order) {
  // XCD co-location: all blocks of a group land on one XCD (XCD = wg % 8),
  // sharing that group's X rows / order entries in its L2. Bijective.
  const int bb = blockIdx.x;
  const int r8 = bb & 7;
  const int k = bb >> 3;               // 0..511
  const int g = ((k >> 6) << 3) | r8;  // group 0..63
  const int ct = (k >> 1) & 31;        // col tile 0..31
  const int mh = k & 1;                // m-tile pair

  const int tid = threadIdx.x;
  const int lane = tid & 63;
  const int wv = tid >> 6;
  const int mt = mh * 2 + wv;  // m-tile 0..3 (rows mt*16..+15)
  const int llo = lane & 15;   // A row / B col within 16-tile
  const int lhi = lane >> 4;   // k-subchunk (k = 8*lhi + e)

  const int cnt = counts[g];

  if (cnt > 0 && mt * 16 < cnt) {
    const int rs = rowstart[g];
    const int mycol = (ct << 4) + llo;
    const float* __restrict__ wp =
        w_mu + ((size_t)g << 18) + ((size_t)mycol << 9) + (lhi << 3);
    const float* __restrict__ w0p = w0_mu + ((size_t)mycol << 9) + (lhi << 3);
    const float bias = b_mu[(g << 9) + mycol];

    float regp = 0.0f;
    if (ct == 0 && mt == 0) {  // fused bias reg-loss, once per group
#pragma unroll
      for (int u = 0; u < 8; ++u) {
        const float d = b_mu[(g << 9) + (u << 6) + lane] - b0_mu[(u << 6) + lane];
        regp += d * d;
      }
    }

    for (int rb = mt * 16; rb < cnt; rb += 64) {  // executes once (cnt <= 64)
      int sl = rb + llo;
      if (sl >= cnt) sl = cnt - 1;  // clamp; duplicates never stored
      const float* __restrict__ xq =
          x + (size_t)order[rs + sl] * F_SZ + (lhi << 3);

      f32x4 acc0 = {0.f, 0.f, 0.f, 0.f};
      f32x4 acc1 = {0.f, 0.f, 0.f, 0.f};
      if (mt == 0 && rb == 0)
        kloop<true>(wp, w0p, xq, acc0, acc1, regp);
      else
        kloop<false>(wp, w0p, xq, acc0, acc1, regp);

      // epilogue: D row = 4*lhi + j, col = llo
#pragma unroll
      for (int j = 0; j < 4; ++j) {
        const int slot = rb + (lhi << 2) + j;
        if (slot < cnt) {
          out[(size_t)order[rs + slot] * U_SZ + mycol] =
              acc0[j] + acc1[j] + bias;
        }
      }
    }

    // wave-level reduce of reg partials (only mt==0 waves hold any)
    if (mt == 0) {
#pragma unroll
      for (int o = 32; o > 0; o >>= 1) regp += __shfl_down(regp, o, 64);
      if (lane == 0) atomicAdd(wsf, (float)cnt * regp);
    }
  }

  // fused finalize: last wave (incl. idle ones) writes the reg-loss scalar
  if (lane == 0) {
    __threadfence();
    if (atomicAdd(done, 1u) == (unsigned)(NWAVES_TOT - 1)) {
      const float v = atomicAdd(wsf, 0.0f);  // coherent device-scope read
      out[(size_t)B_SZ * U_SZ] = REG_STRENGTH * v;
    }
  }
}

extern "C" void kernel_launch(void* const* d_in, const int* in_sizes, int n_in,
                              void* d_out, int out_size, void* d_ws,
                              size_t ws_size, hipStream_t stream) {
  (void)in_sizes; (void)n_in; (void)out_size; (void)ws_size;
  const float* x     = (const float*)d_in[0];
  const int*   gid   = (const int*)d_in[1];
  const float* w_mu  = (const float*)d_in[2];
  const float* b_mu  = (const float*)d_in[3];
  const float* w0_mu = (const float*)d_in[4];
  const float* b0_mu = (const float*)d_in[5];

  float*    wsf      = (float*)d_ws;          // [0]
  unsigned* done     = (unsigned*)d_ws + 1;   // [1]
  int*      counts   = (int*)d_ws + 2;
  int*      rowstart = (int*)d_ws + 2 + G_SZ;
  int*      order    = (int*)d_ws + 2 + 2 * G_SZ;

  hipMemsetAsync(d_ws, 0, 8, stream);
  prep_kernel<<<1, 1024, 0, stream>>>(gid, counts, rowstart, order);
  gemm_kernel<<<NBLOCKS, THREADS, 0, stream>>>(
      x, w_mu, b_mu, w0_mu, b0_mu, (float*)d_out, wsf, done,
      counts, rowstart, order);
}

// Round 4
// 133.949 us; speedup vs baseline: 2.9832x; 2.9832x over previous
//
#include <hip/hip_runtime.h>

// Problem constants (B=2048, F=512, U=512, G=64, REG_STRENGTH=1.0)
#define B_SZ 2048
#define F_SZ 512
#define U_SZ 512
#define G_SZ 64
#define REG_STRENGTH 1.0f

// prep: histogram/prefix/scatter (proven).
// gemm: block = (group g, 64-col tile nt). 256 thr = 4 waves x 16 cols.
//   COALESCED global->reg prefetch (1 step ahead) -> bf16 hi/lo split ->
//   XOR-swizzled LDS planes (double-buffered) -> MFMA fragments.
//   Never load operands from global in fragment layout (r2/r3 lesson:
//   per-lane row gathers = 64 cache lines/instr = 150 GB/s).
#define THREADS 256
#define NBLOCKS 512   // bid = nt*64 + g -> bid%8 = g%8: group's blocks share XCD
#define MC 64         // M rows per chunk (cnt ~ 32, <= 64 in practice)
#define BK 64         // K per step
#define NSTEP (F_SZ / BK)  // 8

typedef float f32x4 __attribute__((ext_vector_type(4)));
typedef __bf16 bf16x8 __attribute__((ext_vector_type(8)));

#define MFMA(a, b, c) __builtin_amdgcn_mfma_f32_16x16x32_bf16((a), (b), (c), 0, 0, 0)

// fp32 -> (hi, lo) bf16 split of a float4 (RNE casts -> v_cvt_pk_bf16_f32).
// Dropped lo*lo matmul term is O(2^-18): fp32-grade accuracy (verified r1-r3).
static __device__ __forceinline__ void split4(const f32x4 v, ushort4* h,
                                              ushort4* l) {
  unsigned short hb[4], lb[4];
#pragma unroll
  for (int i = 0; i < 4; ++i) {
    const __bf16 t = (__bf16)v[i];
    hb[i] = __builtin_bit_cast(unsigned short, t);
    lb[i] = __builtin_bit_cast(unsigned short, (__bf16)(v[i] - (float)t));
  }
  *h = make_ushort4(hb[0], hb[1], hb[2], hb[3]);
  *l = make_ushort4(lb[0], lb[1], lb[2], lb[3]);
}

// ---------------------------------------------------------------------------
// Kernel A: histogram gid -> counts, prefix sum -> rowstart, scatter -> order.
// ---------------------------------------------------------------------------
__global__ __launch_bounds__(1024) void prep_kernel(
    const int* __restrict__ gid, int* __restrict__ counts,
    int* __restrict__ rowstart, int* __restrict__ order) {
  __shared__ int cnt_s[G_SZ];
  __shared__ int cur_s[G_SZ];
  const int tid = threadIdx.x;

  if (tid < G_SZ) cnt_s[tid] = 0;
  __syncthreads();

  for (int b = tid; b < B_SZ; b += 1024) atomicAdd(&cnt_s[gid[b]], 1);
  __syncthreads();

  if (tid == 0) {
    int run = 0;
    for (int g = 0; g < G_SZ; ++g) { cur_s[g] = run; run += cnt_s[g]; }
  }
  __syncthreads();

  if (tid < G_SZ) { counts[tid] = cnt_s[tid]; rowstart[tid] = cur_s[tid]; }
  __syncthreads();  // snapshot rowstart before scatter mutates cur_s

  for (int b = tid; b < B_SZ; b += 1024) {
    int pos = atomicAdd(&cur_s[gid[b]], 1);
    order[pos] = b;
  }
}

// ---------------------------------------------------------------------------
// Kernel B: grouped GEMM (LDS-staged MFMA) + fused reg loss + finalize.
// ---------------------------------------------------------------------------
__global__ __launch_bounds__(THREADS, 2) void gemm_kernel(
    const float* __restrict__ x, const float* __restrict__ w_mu,
    const float* __restrict__ b_mu, const float* __restrict__ w0_mu,
    const float* __restrict__ b0_mu, float* __restrict__ out,
    float* __restrict__ wsf, unsigned* __restrict__ done,
    const int* __restrict__ counts, const int* __restrict__ rowstart,
    const int* __restrict__ order) {
  // bf16 planes, row stride 64 elems (128 B), XOR-swizzled. 4*2*8KB = 64 KB.
  __shared__ __align__(16) unsigned short WH[2][MC * BK];
  __shared__ __align__(16) unsigned short WL[2][MC * BK];
  __shared__ __align__(16) unsigned short XH[2][MC * BK];
  __shared__ __align__(16) unsigned short XL[2][MC * BK];
  __shared__ float red_s[4];

  const int bid = blockIdx.x;
  const int g = bid & 63;   // blocks of a group: bid % 8 == g % 8 -> one XCD
  const int nt = bid >> 6;  // 64-col tile 0..7
  const int n0 = nt << 6;

  const int tid = threadIdx.x;
  const int lane = tid & 63;
  const int wv = tid >> 6;    // wave -> 16-col slice
  const int llo = lane & 15;  // frag row/col within 16-tile
  const int lhi = lane >> 4;  // frag k-subchunk

  const int srow = tid >> 4;  // staging: row base 0..15 (u adds 16,32,48)
  const int kq = tid & 15;    // staging: float4 within row (coalesced)

  const int cnt = counts[g];

  if (cnt > 0) {
    const int rs = rowstart[g];
    const int mycol = n0 + (wv << 4) + llo;
    const float* __restrict__ wgp =
        w_mu + ((size_t)g << 18) + (size_t)(n0 + srow) * F_SZ + (kq << 2);
    const float* __restrict__ w0p =
        w0_mu + (size_t)(n0 + srow) * F_SZ + (kq << 2);

    float regp = 0.0f;
    if (nt == 0) {  // fused bias reg-loss, once per group
#pragma unroll
      for (int u = 0; u < 2; ++u) {
        const int idx = (u << 8) + tid;
        const float d = b_mu[(g << 9) + idx] - b0_mu[idx];
        regp += d * d;
      }
    }

    for (int mc = 0; mc < cnt; mc += MC) {  // one pass in practice (cnt<=64)
      const int rc = min(MC, cnt - mc);
      const int mts = (rc + 15) >> 4;       // active 16-row m-tiles
      const bool doreg = (mc == 0);

      const float* xp[4];
#pragma unroll
      for (int u = 0; u < 4; ++u) {
        int sl = mc + srow + (u << 4);
        if (sl >= cnt) sl = cnt - 1;  // dup row; guarded at store
        xp[u] = x + (size_t)order[rs + sl] * F_SZ + (kq << 2);
      }

      f32x4 acc[4];
#pragma unroll
      for (int m = 0; m < 4; ++m) acc[m] = (f32x4){0.f, 0.f, 0.f, 0.f};

      // ---- prologue: coalesced load + stage step 0 into buffer 0 ----
      f32x4 wr[4], xr[4];
#pragma unroll
      for (int u = 0; u < 4; ++u) wr[u] = *(const f32x4*)(wgp + (u << 13));
#pragma unroll
      for (int u = 0; u < 4; ++u) xr[u] = *(const f32x4*)(xp[u]);
      if (doreg) {  // fused W reg-loss on the staged registers
#pragma unroll
        for (int u = 0; u < 4; ++u) {
          const f32x4 z = *(const f32x4*)(w0p + (u << 13));
#pragma unroll
          for (int i = 0; i < 4; ++i) {
            const float d = wr[u][i] - z[i];
            regp += d * d;
          }
        }
      }
#pragma unroll
      for (int u = 0; u < 4; ++u) {
        const int row = srow + (u << 4);
        int byte = (row << 7) + (kq << 3);
        byte ^= (row & 7) << 4;
        ushort4 h, l;
        split4(wr[u], &h, &l);
        *(ushort4*)((char*)&WH[0][0] + byte) = h;
        *(ushort4*)((char*)&WL[0][0] + byte) = l;
        split4(xr[u], &h, &l);
        *(ushort4*)((char*)&XH[0][0] + byte) = h;
        *(ushort4*)((char*)&XL[0][0] + byte) = l;
      }
      __syncthreads();

#pragma unroll 2
      for (int s = 0; s < NSTEP; ++s) {
        const int p = s & 1;
        // (1) issue next step's coalesced loads (land during compute)
        if (s + 1 < NSTEP) {
          const int ko = (s + 1) << 6;
#pragma unroll
          for (int u = 0; u < 4; ++u)
            wr[u] = *(const f32x4*)(wgp + (u << 13) + ko);
#pragma unroll
          for (int u = 0; u < 4; ++u) xr[u] = *(const f32x4*)(xp[u] + ko);
        }
        // (2) compute on buffer p: fragments from swizzled LDS
#pragma unroll
        for (int kk = 0; kk < 2; ++kk) {
          const int wrow = (wv << 4) + llo;
          int wb = (wrow << 7) + (kk << 6) + (lhi << 4);
          wb ^= (wrow & 7) << 4;
          const bf16x8 wh = *(const bf16x8*)((const char*)&WH[p][0] + wb);
          const bf16x8 wl = *(const bf16x8*)((const char*)&WL[p][0] + wb);
#pragma unroll
          for (int m = 0; m < 4; ++m) {
            if (m < mts) {
              const int ar = (m << 4) + llo;
              int ab = (ar << 7) + (kk << 6) + (lhi << 4);
              ab ^= (ar & 7) << 4;
              const bf16x8 ah = *(const bf16x8*)((const char*)&XH[p][0] + ab);
              const bf16x8 al = *(const bf16x8*)((const char*)&XL[p][0] + ab);
              acc[m] = MFMA(ah, wh, acc[m]);
              acc[m] = MFMA(ah, wl, acc[m]);
              acc[m] = MFMA(al, wh, acc[m]);
            }
          }
        }
        // (3) reg-loss + stage prefetched regs into the other buffer
        if (s + 1 < NSTEP) {
          if (doreg) {
            const int ko = (s + 1) << 6;
#pragma unroll
            for (int u = 0; u < 4; ++u) {
              const f32x4 z = *(const f32x4*)(w0p + (u << 13) + ko);
#pragma unroll
              for (int i = 0; i < 4; ++i) {
                const float d = wr[u][i] - z[i];
                regp += d * d;
              }
            }
          }
          const int q = p ^ 1;
#pragma unroll
          for (int u = 0; u < 4; ++u) {
            const int row = srow + (u << 4);
            int byte = (row << 7) + (kq << 3);
            byte ^= (row & 7) << 4;
            ushort4 h, l;
            split4(wr[u], &h, &l);
            *(ushort4*)((char*)&WH[q][0] + byte) = h;
            *(ushort4*)((char*)&WL[q][0] + byte) = l;
            split4(xr[u], &h, &l);
            *(ushort4*)((char*)&XH[q][0] + byte) = h;
            *(ushort4*)((char*)&XL[q][0] + byte) = l;
          }
        }
        __syncthreads();
      }

      // ---- epilogue: D row = 4*lhi + j, col = llo; scatter by order ----
      const float bias = b_mu[(g << 9) + mycol];
#pragma unroll
      for (int m = 0; m < 4; ++m) {
        if (m < mts) {
#pragma unroll
          for (int j = 0; j < 4; ++j) {
            const int slot = mc + (m << 4) + (lhi << 2) + j;
            if (slot < cnt) {
              out[(size_t)order[rs + slot] * U_SZ + mycol] = acc[m][j] + bias;
            }
          }
        }
      }
    }

    // ---- block-reduce reg partials, weight by cnt, one atomic ----
#pragma unroll
    for (int o = 32; o > 0; o >>= 1) regp += __shfl_down(regp, o, 64);
    if (lane == 0) red_s[wv] = regp;
    __syncthreads();
    if (tid == 0)
      atomicAdd(wsf, (float)cnt * (red_s[0] + red_s[1] + red_s[2] + red_s[3]));
  }

  // fused finalize: last block writes the reg-loss scalar
  if (tid == 0) {
    __threadfence();
    if (atomicAdd(done, 1u) == (unsigned)(NBLOCKS - 1)) {
      const float v = atomicAdd(wsf, 0.0f);  // coherent device-scope read
      out[(size_t)B_SZ * U_SZ] = REG_STRENGTH * v;
    }
  }
}

extern "C" void kernel_launch(void* const* d_in, const int* in_sizes, int n_in,
                              void* d_out, int out_size, void* d_ws,
                              size_t ws_size, hipStream_t stream) {
  (void)in_sizes; (void)n_in; (void)out_size; (void)ws_size;
  const float* x     = (const float*)d_in[0];
  const int*   gid   = (const int*)d_in[1];
  const float* w_mu  = (const float*)d_in[2];
  const float* b_mu  = (const float*)d_in[3];
  const float* w0_mu = (const float*)d_in[4];
  const float* b0_mu = (const float*)d_in[5];

  float*    wsf      = (float*)d_ws;         // [0]
  unsigned* done     = (unsigned*)d_ws + 1;  // [1]
  int*      counts   = (int*)d_ws + 2;
  int*      rowstart = (int*)d_ws + 2 + G_SZ;
  int*      order    = (int*)d_ws + 2 + 2 * G_SZ;

  hipMemsetAsync(d_ws, 0, 8, stream);
  prep_kernel<<<1, 1024, 0, stream>>>(gid, counts, rowstart, order);
  gemm_kernel<<<NBLOCKS, THREADS, 0, stream>>>(
      x, w_mu, b_mu, w0_mu, b0_mu, (float*)d_out, wsf, done,
      counts, rowstart, order);
}